// Round 1
// baseline (677.276 us; speedup 1.0000x reference)
//
#include <hip/hip_runtime.h>

typedef unsigned short u16;
typedef __attribute__((ext_vector_type(8))) short short8;
typedef __attribute__((ext_vector_type(4))) float f32x4;

// Problem constants: B=2, T=2048, C=2048, H=16, HD=128
#define TSEQ 2048
#define NHEAD 16
#define HDIM 128

__device__ __forceinline__ u16 f2bf(float x) {
    unsigned u = __float_as_uint(x);
    return (u16)((u + 0x7fffu + ((u >> 16) & 1u)) >> 16);
}
__device__ __forceinline__ float b2f(u16 h) {
    return __uint_as_float(((unsigned)h) << 16);
}
__device__ __forceinline__ void async16(const void* g, void* l) {
    __builtin_amdgcn_global_load_lds((__attribute__((address_space(1))) void*)(void*)g,
                                     (__attribute__((address_space(3))) void*)l, 16, 0, 0);
}
__device__ __forceinline__ f32x4 zero4() {
    f32x4 z = {0.f, 0.f, 0.f, 0.f};
    return z;
}

// ---------------- cast x (f32 -> bf16), vectorized ----------------
__global__ void cast_bf16(const float4* __restrict__ in, ushort4* __restrict__ out, int n4) {
    int i = blockIdx.x * 256 + threadIdx.x;
    if (i < n4) {
        float4 v = in[i];
        ushort4 o;
        o.x = f2bf(v.x); o.y = f2bf(v.y); o.z = f2bf(v.z); o.w = f2bf(v.w);
        out[i] = o;
    }
}

// ---------------- transpose + cast: in f32 [K][N] -> out bf16 [N][K] ----------------
__global__ void transpose_cast(const float* __restrict__ in, u16* __restrict__ out, int K, int N) {
    __shared__ float tile[64][65];
    int n0 = blockIdx.x * 64, k0 = blockIdx.y * 64;
    int tx = threadIdx.x & 63, ty = threadIdx.x >> 6;  // ty 0..3
#pragma unroll
    for (int i = 0; i < 16; i++) {
        int r = ty + i * 4;
        tile[r][tx] = in[(size_t)(k0 + r) * N + n0 + tx];
    }
    __syncthreads();
#pragma unroll
    for (int i = 0; i < 16; i++) {
        int r = ty + i * 4;
        out[(size_t)(n0 + r) * K + k0 + tx] = f2bf(tile[tx][r]);
    }
}

// ---------------- GEMM: C = A(MxK) * Bt(NxK)^T + bias ----------------
// MODE 0: scatter bf16 into qb/kb/vb [bh][t][d]  (N=6144 = q|k|v)
// MODE 1: f32 out row-major [M][N]
template <int MODE>
__global__ __launch_bounds__(256) void gemm_bt(
    const u16* __restrict__ A, const u16* __restrict__ Bt, const float* __restrict__ bias,
    float* __restrict__ outf, u16* __restrict__ qb, u16* __restrict__ kb, u16* __restrict__ vb,
    int M, int N, int K) {
    __shared__ u16 As[128 * 32];
    __shared__ u16 Bs[128 * 32];
    const int tid = threadIdx.x;
    const int wave = tid >> 6, lane = tid & 63;
    const int low = lane & 15, quad = lane >> 4;
    const int m0 = blockIdx.y * 128, n0 = blockIdx.x * 128;
    const int wm = (wave >> 1) * 64, wn = (wave & 1) * 64;
    const int ldr = lane >> 2;          // row within 16-row chunk
    const int ldc = (lane & 3) * 8;     // col (elems) within 32

    f32x4 acc[4][4];
#pragma unroll
    for (int i = 0; i < 4; i++)
#pragma unroll
        for (int j = 0; j < 4; j++) acc[i][j] = zero4();

    for (int k0 = 0; k0 < K; k0 += 32) {
#pragma unroll
        for (int c = 0; c < 2; ++c) {
            const int chunk = wave * 2 + c;
            const int row = chunk * 16 + ldr;
            async16(A + (size_t)(m0 + row) * K + k0 + ldc, As + chunk * 512);
            async16(Bt + (size_t)(n0 + row) * K + k0 + ldc, Bs + chunk * 512);
        }
        __syncthreads();
        short8 af[4], bfv[4];
#pragma unroll
        for (int i = 0; i < 4; i++) af[i] = *(const short8*)(As + (wm + i * 16 + low) * 32 + quad * 8);
#pragma unroll
        for (int j = 0; j < 4; j++) bfv[j] = *(const short8*)(Bs + (wn + j * 16 + low) * 32 + quad * 8);
#pragma unroll
        for (int i = 0; i < 4; i++)
#pragma unroll
            for (int j = 0; j < 4; j++)
                acc[i][j] = __builtin_amdgcn_mfma_f32_16x16x32_bf16(af[i], bfv[j], acc[i][j], 0, 0, 0);
        __syncthreads();
    }

#pragma unroll
    for (int j = 0; j < 4; j++) {
        const int ng = n0 + wn + j * 16 + low;
        const float bv = bias[ng];
#pragma unroll
        for (int i = 0; i < 4; i++) {
            const int rbase = m0 + wm + i * 16 + quad * 4;
#pragma unroll
            for (int r = 0; r < 4; r++) {
                float v = acc[i][j][r] + bv;
                int rowg = rbase + r;  // = b*T + t
                if (MODE == 1) {
                    outf[(size_t)rowg * N + ng] = v;
                } else {
                    int which = ng >> 11;          // 0=q 1=k 2=v
                    int hd = ng & 2047;
                    int bq = rowg >> 11, t = rowg & 2047;
                    u16* dst = (which == 0) ? qb : (which == 1) ? kb : vb;
                    dst[(((size_t)(bq * NHEAD + (hd >> 7))) * TSEQ + t) * HDIM + (hd & 127)] = f2bf(v);
                }
            }
        }
    }
}

// ---------------- RoPE in-place on q,k [bh][t][d], interleaved pairs ----------------
__global__ void rope_inplace(u16* __restrict__ qb, u16* __restrict__ kb,
                             const float* __restrict__ cosp, const float* __restrict__ sinp) {
    int idx = blockIdx.x * 256 + threadIdx.x;  // (bh*T + t)*64 + i
    int i = idx & 63;
    int bt = idx >> 6;
    int t = bt & (TSEQ - 1);
    size_t o = (size_t)bt * HDIM + 2 * i;
    float c = cosp[t * 64 + i], s = sinp[t * 64 + i];
    float q0 = b2f(qb[o]), q1 = b2f(qb[o + 1]);
    qb[o] = f2bf(q0 * c - q1 * s);
    qb[o + 1] = f2bf(q0 * s + q1 * c);
    float k0 = b2f(kb[o]), k1 = b2f(kb[o + 1]);
    kb[o] = f2bf(k0 * c - k1 * s);
    kb[o + 1] = f2bf(k0 * s + k1 * c);
}

// ---------------- V transpose: vtmp [bh][t][d] -> vT [bh][d][t] ----------------
__global__ void vtrans(const u16* __restrict__ vtmp, u16* __restrict__ vT) {
    __shared__ u16 tile[64][66];
    int bid = blockIdx.x;
    int tt = bid & 31;
    int dt = (bid >> 5) & 1;
    int bh = bid >> 6;
    int t0 = tt * 64, d0 = dt * 64;
    int tx = threadIdx.x & 63, ty = threadIdx.x >> 6;
    size_t ibase = ((size_t)bh * TSEQ + t0) * HDIM + d0;
#pragma unroll
    for (int i = 0; i < 16; i++) {
        int r = ty + i * 4;
        tile[r][tx] = vtmp[ibase + (size_t)r * HDIM + tx];
    }
    __syncthreads();
    size_t obase = ((size_t)bh * HDIM + d0) * TSEQ + t0;
#pragma unroll
    for (int i = 0; i < 16; i++) {
        int r = ty + i * 4;
        vT[obase + (size_t)r * TSEQ + tx] = tile[tx][r];
    }
}

// ---------------- Flash attention (causal), 1 wave = 16 q rows ----------------
__global__ __launch_bounds__(256) void flash_attn(const u16* __restrict__ qb, const u16* __restrict__ kb,
                                                  const u16* __restrict__ vT, u16* __restrict__ y) {
    __shared__ u16 Pl[4][2][512];  // per-wave double-buffered P (16x32 bf16)
    const int wave = threadIdx.x >> 6, lane = threadIdx.x & 63;
    const int low = lane & 15, quad = lane >> 4;
    const int bh = blockIdx.x, qt = blockIdx.y;
    const int b = bh >> 4, h = bh & 15;
    const int q0 = qt * 64 + wave * 16;
    const float scale = 0.08838834764831845f;  // 1/sqrt(128)

    const u16* Qp = qb + ((size_t)bh * TSEQ + q0) * HDIM;
    short8 qf[4];
#pragma unroll
    for (int c = 0; c < 4; c++) qf[c] = *(const short8*)(Qp + (size_t)low * HDIM + c * 32 + quad * 8);

    f32x4 o[8];
#pragma unroll
    for (int d = 0; d < 8; d++) o[d] = zero4();
    float m_i[4], l_i[4];
#pragma unroll
    for (int r = 0; r < 4; r++) { m_i[r] = -1e30f; l_i[r] = 0.f; }

    const u16* Kb = kb + (size_t)bh * TSEQ * HDIM;
    const u16* Vb = vT + (size_t)bh * HDIM * TSEQ;
    u16* Pw = &Pl[wave][0][0];
    const int ntiles = 2 * qt + 2;  // same for all 4 waves in block

    for (int kt = 0; kt < ntiles; ++kt) {
        const int kv0 = kt * 32;
        f32x4 s[2];
        s[0] = zero4(); s[1] = zero4();
#pragma unroll
        for (int half = 0; half < 2; half++) {
            const u16* Kp = Kb + (size_t)(kv0 + half * 16 + low) * HDIM;
#pragma unroll
            for (int c = 0; c < 4; c++) {
                short8 kf = *(const short8*)(Kp + c * 32 + quad * 8);
                s[half] = __builtin_amdgcn_mfma_f32_16x16x32_bf16(qf[c], kf, s[half], 0, 0, 0);
            }
        }
        u16* Pb = Pw + (kt & 1) * 512;
        float alpha[4];
#pragma unroll
        for (int r = 0; r < 4; r++) {
            const int qg = q0 + quad * 4 + r;
            float sv0 = (kv0 + low <= qg) ? s[0][r] * scale : -1e30f;
            float sv1 = (kv0 + 16 + low <= qg) ? s[1][r] * scale : -1e30f;
            float rm = fmaxf(sv0, sv1);
            rm = fmaxf(rm, __shfl_xor(rm, 1, 64));
            rm = fmaxf(rm, __shfl_xor(rm, 2, 64));
            rm = fmaxf(rm, __shfl_xor(rm, 4, 64));
            rm = fmaxf(rm, __shfl_xor(rm, 8, 64));
            float mnew = fmaxf(m_i[r], rm);
            alpha[r] = __expf(m_i[r] - mnew);
            float p0 = __expf(sv0 - mnew);
            float p1 = __expf(sv1 - mnew);
            m_i[r] = mnew;
            float rs = p0 + p1;
            rs += __shfl_xor(rs, 1, 64);
            rs += __shfl_xor(rs, 2, 64);
            rs += __shfl_xor(rs, 4, 64);
            rs += __shfl_xor(rs, 8, 64);
            l_i[r] = l_i[r] * alpha[r] + rs;
            Pb[(quad * 4 + r) * 32 + low] = f2bf(p0);
            Pb[(quad * 4 + r) * 32 + 16 + low] = f2bf(p1);
        }
        __threadfence_block();  // order per-wave LDS writes before reads
#pragma unroll
        for (int d = 0; d < 8; ++d)
#pragma unroll
            for (int r = 0; r < 4; r++) o[d][r] *= alpha[r];
        short8 pf = *(const short8*)(Pb + low * 32 + quad * 8);
#pragma unroll
        for (int d = 0; d < 8; ++d) {
            short8 vf = *(const short8*)(Vb + (size_t)(d * 16 + low) * TSEQ + kv0 + quad * 8);
            o[d] = __builtin_amdgcn_mfma_f32_16x16x32_bf16(pf, vf, o[d], 0, 0, 0);
        }
    }

    // epilogue: y[b*T + q][h*128 + d] bf16
#pragma unroll
    for (int r = 0; r < 4; r++) {
        float inv = 1.0f / l_i[r];
        size_t row = (size_t)(b * TSEQ + q0 + quad * 4 + r);
        u16* yp = y + row * 2048 + h * HDIM;
#pragma unroll
        for (int d = 0; d < 8; ++d) yp[d * 16 + low] = f2bf(o[d][r] * inv);
    }
}

extern "C" void kernel_launch(void* const* d_in, const int* in_sizes, int n_in,
                              void* d_out, int out_size, void* d_ws, size_t ws_size,
                              hipStream_t stream) {
    const float* x = (const float*)d_in[0];
    const float* Wa = (const float*)d_in[1];
    const float* ba = (const float*)d_in[2];
    const float* Wp = (const float*)d_in[3];
    const float* bp = (const float*)d_in[4];
    const float* cs = (const float*)d_in[5];
    const float* sn = (const float*)d_in[6];
    float* out = (float*)d_out;

    // workspace layout (u16 elems); total 58,720,256 u16 = 112 MiB
    u16* xb = (u16*)d_ws;             // 8,388,608  (x bf16; reused later as y)
    u16* Wab = xb + 8388608;          // 12,582,912 (W_attn^T bf16 [6144][2048])
    u16* Wpb = Wab + 12582912;        // 4,194,304  (W_proj^T bf16 [2048][2048])
    u16* qb = Wpb + 4194304;          // 8,388,608  [bh][t][d]
    u16* kb = qb + 8388608;           // 8,388,608  [bh][t][d]
    u16* vtmp = kb + 8388608;         // 8,388,608  [bh][t][d]
    u16* vT = vtmp + 8388608;         // 8,388,608  [bh][d][t]
    u16* y = xb;                      // reuse x buffer for attention output

    cast_bf16<<<8192, 256, 0, stream>>>((const float4*)x, (ushort4*)xb, 2097152);
    transpose_cast<<<dim3(96, 32), 256, 0, stream>>>(Wa, Wab, 2048, 6144);
    transpose_cast<<<dim3(32, 32), 256, 0, stream>>>(Wp, Wpb, 2048, 2048);
    gemm_bt<0><<<dim3(48, 32), 256, 0, stream>>>(xb, Wab, ba, nullptr, qb, kb, vtmp, 4096, 6144, 2048);
    rope_inplace<<<16384, 256, 0, stream>>>(qb, kb, cs, sn);
    vtrans<<<2048, 256, 0, stream>>>(vtmp, vT);
    flash_attn<<<dim3(32, 32), 256, 0, stream>>>(qb, kb, vT, y);
    gemm_bt<1><<<dim3(16, 32), 256, 0, stream>>>(y, Wpb, bp, out, nullptr, nullptr, nullptr, 4096, 2048, 2048);
}

// Round 2
// 463.749 us; speedup vs baseline: 1.4604x; 1.4604x over previous
//
#include <hip/hip_runtime.h>

typedef unsigned short u16;
typedef __attribute__((ext_vector_type(8))) short short8;
typedef __attribute__((ext_vector_type(4))) float f32x4;

// Problem constants: B=2, T=2048, C=2048, H=16, HD=128
#define TSEQ 2048
#define NHEAD 16
#define HDIM 128

__device__ __forceinline__ u16 f2bf(float x) {
    unsigned u = __float_as_uint(x);
    return (u16)((u + 0x7fffu + ((u >> 16) & 1u)) >> 16);
}
__device__ __forceinline__ float b2f(u16 h) {
    return __uint_as_float(((unsigned)h) << 16);
}
__device__ __forceinline__ void async16(const void* g, void* l) {
    __builtin_amdgcn_global_load_lds((__attribute__((address_space(1))) void*)(void*)g,
                                     (__attribute__((address_space(3))) void*)l, 16, 0, 0);
}
__device__ __forceinline__ f32x4 zero4() {
    f32x4 z = {0.f, 0.f, 0.f, 0.f};
    return z;
}

// DPP cross-lane (16-lane group reductions), no LDS traffic
template <int CTRL>
__device__ __forceinline__ float dppf(float x) {
    return __int_as_float(__builtin_amdgcn_mov_dpp(__float_as_int(x), CTRL, 0xf, 0xf, true));
}
__device__ __forceinline__ float dpp_max16(float x) {
    x = fmaxf(x, dppf<0xB1>(x));   // quad_perm xor1
    x = fmaxf(x, dppf<0x4E>(x));   // quad_perm xor2
    x = fmaxf(x, dppf<0x141>(x));  // row_half_mirror (~xor4)
    x = fmaxf(x, dppf<0x140>(x));  // row_mirror (~xor8)
    return x;
}
__device__ __forceinline__ float dpp_sum16(float x) {
    x += dppf<0xB1>(x);
    x += dppf<0x4E>(x);
    x += dppf<0x141>(x);
    x += dppf<0x140>(x);
    return x;
}

// ---------------- cast x (f32 -> bf16), vectorized ----------------
__global__ void cast_bf16(const float4* __restrict__ in, ushort4* __restrict__ out, int n4) {
    int i = blockIdx.x * 256 + threadIdx.x;
    if (i < n4) {
        float4 v = in[i];
        ushort4 o;
        o.x = f2bf(v.x); o.y = f2bf(v.y); o.z = f2bf(v.z); o.w = f2bf(v.w);
        out[i] = o;
    }
}

// ---------------- transpose + cast: in f32 [K][N] -> out bf16 [N][K] ----------------
__global__ void transpose_cast(const float* __restrict__ in, u16* __restrict__ out, int K, int N) {
    __shared__ float tile[64][65];
    int n0 = blockIdx.x * 64, k0 = blockIdx.y * 64;
    int tx = threadIdx.x & 63, ty = threadIdx.x >> 6;
#pragma unroll
    for (int i = 0; i < 16; i++) {
        int r = ty + i * 4;
        tile[r][tx] = in[(size_t)(k0 + r) * N + n0 + tx];
    }
    __syncthreads();
#pragma unroll
    for (int i = 0; i < 16; i++) {
        int r = ty + i * 4;
        out[(size_t)(n0 + r) * K + k0 + tx] = f2bf(tile[tx][r]);
    }
}

// ---------------- GEMM: C = A(MxK) * Bt(NxK)^T + bias ----------------
template <int MODE>
__global__ __launch_bounds__(256) void gemm_bt(
    const u16* __restrict__ A, const u16* __restrict__ Bt, const float* __restrict__ bias,
    float* __restrict__ outf, u16* __restrict__ qb, u16* __restrict__ kb, u16* __restrict__ vb,
    int M, int N, int K) {
    __shared__ u16 As[128 * 32];
    __shared__ u16 Bs[128 * 32];
    const int tid = threadIdx.x;
    const int wave = tid >> 6, lane = tid & 63;
    const int low = lane & 15, quad = lane >> 4;
    const int m0 = blockIdx.y * 128, n0 = blockIdx.x * 128;
    const int wm = (wave >> 1) * 64, wn = (wave & 1) * 64;
    const int ldr = lane >> 2;
    const int ldc = (lane & 3) * 8;

    f32x4 acc[4][4];
#pragma unroll
    for (int i = 0; i < 4; i++)
#pragma unroll
        for (int j = 0; j < 4; j++) acc[i][j] = zero4();

    for (int k0 = 0; k0 < K; k0 += 32) {
#pragma unroll
        for (int c = 0; c < 2; ++c) {
            const int chunk = wave * 2 + c;
            const int row = chunk * 16 + ldr;
            async16(A + (size_t)(m0 + row) * K + k0 + ldc, As + chunk * 512);
            async16(Bt + (size_t)(n0 + row) * K + k0 + ldc, Bs + chunk * 512);
        }
        __syncthreads();
        short8 af[4], bfv[4];
#pragma unroll
        for (int i = 0; i < 4; i++) af[i] = *(const short8*)(As + (wm + i * 16 + low) * 32 + quad * 8);
#pragma unroll
        for (int j = 0; j < 4; j++) bfv[j] = *(const short8*)(Bs + (wn + j * 16 + low) * 32 + quad * 8);
#pragma unroll
        for (int i = 0; i < 4; i++)
#pragma unroll
            for (int j = 0; j < 4; j++)
                acc[i][j] = __builtin_amdgcn_mfma_f32_16x16x32_bf16(af[i], bfv[j], acc[i][j], 0, 0, 0);
        __syncthreads();
    }

#pragma unroll
    for (int j = 0; j < 4; j++) {
        const int ng = n0 + wn + j * 16 + low;
        const float bv = bias[ng];
#pragma unroll
        for (int i = 0; i < 4; i++) {
            const int rbase = m0 + wm + i * 16 + quad * 4;
#pragma unroll
            for (int r = 0; r < 4; r++) {
                float v = acc[i][j][r] + bv;
                int rowg = rbase + r;
                if (MODE == 1) {
                    outf[(size_t)rowg * N + ng] = v;
                } else {
                    int which = ng >> 11;
                    int hd = ng & 2047;
                    int bq = rowg >> 11, t = rowg & 2047;
                    u16* dst = (which == 0) ? qb : (which == 1) ? kb : vb;
                    dst[(((size_t)(bq * NHEAD + (hd >> 7))) * TSEQ + t) * HDIM + (hd & 127)] = f2bf(v);
                }
            }
        }
    }
}

// ---------------- RoPE in-place on q,k [bh][t][d], interleaved pairs ----------------
__global__ void rope_inplace(u16* __restrict__ qb, u16* __restrict__ kb,
                             const float* __restrict__ cosp, const float* __restrict__ sinp) {
    int idx = blockIdx.x * 256 + threadIdx.x;
    int i = idx & 63;
    int bt = idx >> 6;
    int t = bt & (TSEQ - 1);
    size_t o = (size_t)bt * HDIM + 2 * i;
    float c = cosp[t * 64 + i], s = sinp[t * 64 + i];
    float q0 = b2f(qb[o]), q1 = b2f(qb[o + 1]);
    qb[o] = f2bf(q0 * c - q1 * s);
    qb[o + 1] = f2bf(q0 * s + q1 * c);
    float k0 = b2f(kb[o]), k1 = b2f(kb[o + 1]);
    kb[o] = f2bf(k0 * c - k1 * s);
    kb[o + 1] = f2bf(k0 * s + k1 * c);
}

// ---------------- V transpose: vtmp [bh][t][d] -> vT [bh][d][t] ----------------
__global__ void vtrans(const u16* __restrict__ vtmp, u16* __restrict__ vT) {
    __shared__ u16 tile[64][66];
    int bid = blockIdx.x;
    int tt = bid & 31;
    int dt = (bid >> 5) & 1;
    int bh = bid >> 6;
    int t0 = tt * 64, d0 = dt * 64;
    int tx = threadIdx.x & 63, ty = threadIdx.x >> 6;
    size_t ibase = ((size_t)bh * TSEQ + t0) * HDIM + d0;
#pragma unroll
    for (int i = 0; i < 16; i++) {
        int r = ty + i * 4;
        tile[r][tx] = vtmp[ibase + (size_t)r * HDIM + tx];
    }
    __syncthreads();
    size_t obase = ((size_t)bh * HDIM + d0) * TSEQ + t0;
#pragma unroll
    for (int i = 0; i < 16; i++) {
        int r = ty + i * 4;
        vT[obase + (size_t)r * TSEQ + tx] = tile[tx][r];
    }
}

// ---------------- Flash attention v2: LDS-staged K/V, 64-key tiles, DPP softmax ----------------
// Block = 4 waves = 64 q rows; K tile [64][128] + V^T tile [128][64] staged via
// global_load_lds (source-chunk XOR swizzle so b128 frag reads are uniform across banks).
__global__ __launch_bounds__(256) void flash_attn(const u16* __restrict__ qb, const u16* __restrict__ kb,
                                                  const u16* __restrict__ vT, u16* __restrict__ y) {
    __shared__ u16 Ks[64 * 128];      // [key][d], chunks xor-swizzled by (key&7)
    __shared__ u16 Vs[128 * 64];      // [d][key], chunks xor-swizzled by (d&7)
    __shared__ u16 Ps[4][16 * 72];    // per-wave P 16x64, row stride 72 (16B-aligned, uniform banks)
    const int tid = threadIdx.x;
    const int wave = tid >> 6, lane = tid & 63;
    const int low = lane & 15, quad = lane >> 4;
    const int bh = blockIdx.x;
    const int qt = 31 - blockIdx.y;          // longest blocks first
    const int q0 = qt * 64 + wave * 16;
    const float scale2 = 0.08838834764831845f * 1.44269504088896f;  // 1/sqrt(128) * log2(e)

    const u16* Qp = qb + ((size_t)bh * TSEQ + q0) * HDIM;
    short8 qf[4];
#pragma unroll
    for (int c = 0; c < 4; c++) qf[c] = *(const short8*)(Qp + (size_t)low * HDIM + c * 32 + quad * 8);

    f32x4 o[8];
#pragma unroll
    for (int d = 0; d < 8; d++) o[d] = zero4();
    float m_i[4], l_i[4];
#pragma unroll
    for (int r = 0; r < 4; r++) { m_i[r] = -1e30f; l_i[r] = 0.f; }

    const u16* Kb = kb + (size_t)bh * TSEQ * HDIM;
    const u16* Vb = vT + (size_t)bh * HDIM * TSEQ;
    u16* Pw = &Ps[wave][0];
    const int ntiles = qt + 1;

    // staging thread->slot mapping (contiguous LDS in tid order: lds_u16 = j*2048 + tid*8)
    const int krow = tid >> 4, kchunk = tid & 15;   // K: 16 rows x 16 chunks per issue
    const int vrow = tid >> 3, vchunk = tid & 7;    // V: 32 rows x 8 chunks per issue

    for (int kt = 0; kt < ntiles; ++kt) {
        const int kv0 = kt * 64;
#pragma unroll
        for (int j = 0; j < 4; j++) {
            const int row = j * 16 + krow;
            const int gc = kchunk ^ (row & 7);
            async16(Kb + (size_t)(kv0 + row) * HDIM + gc * 8, Ks + row * 128 + kchunk * 8);
        }
#pragma unroll
        for (int j = 0; j < 4; j++) {
            const int d = j * 32 + vrow;
            const int gc = vchunk ^ (d & 7);
            async16(Vb + (size_t)d * TSEQ + kv0 + gc * 8, Vs + d * 64 + vchunk * 8);
        }
        __syncthreads();  // drains global_load_lds (vmcnt) + aligns waves

        // ---- QK^T: S[16q x 64k] as 4 C-tiles ----
        f32x4 s[4];
#pragma unroll
        for (int h = 0; h < 4; h++) s[h] = zero4();
#pragma unroll
        for (int h = 0; h < 4; h++) {
            const int row = h * 16 + low;
#pragma unroll
            for (int c = 0; c < 4; c++) {
                const int cc = c * 4 + quad;
                short8 kf = *(const short8*)(Ks + row * 128 + (cc ^ (row & 7)) * 8);
                s[h] = __builtin_amdgcn_mfma_f32_16x16x32_bf16(qf[c], kf, s[h], 0, 0, 0);
            }
        }

        // ---- online softmax (exp2 domain), DPP reductions ----
        float alpha[4];
#pragma unroll
        for (int r = 0; r < 4; r++) {
            const int qg = q0 + quad * 4 + r;
            float sv[4];
#pragma unroll
            for (int h = 0; h < 4; h++)
                sv[h] = (kv0 + h * 16 + low <= qg) ? s[h][r] * scale2 : -1e30f;
            float mx = fmaxf(fmaxf(sv[0], sv[1]), fmaxf(sv[2], sv[3]));
            mx = dpp_max16(mx);
            float mnew = fmaxf(m_i[r], mx);
            alpha[r] = exp2f(m_i[r] - mnew);
            m_i[r] = mnew;
            float p0 = exp2f(sv[0] - mnew);
            float p1 = exp2f(sv[1] - mnew);
            float p2 = exp2f(sv[2] - mnew);
            float p3 = exp2f(sv[3] - mnew);
            float rs = (p0 + p1) + (p2 + p3);
            rs = dpp_sum16(rs);
            l_i[r] = l_i[r] * alpha[r] + rs;
            const int prow = (quad * 4 + r) * 72;
            Pw[prow + low] = f2bf(p0);
            Pw[prow + 16 + low] = f2bf(p1);
            Pw[prow + 32 + low] = f2bf(p2);
            Pw[prow + 48 + low] = f2bf(p3);
        }
        __threadfence_block();  // order per-wave LDS P writes before reads

#pragma unroll
        for (int d = 0; d < 8; ++d)
#pragma unroll
            for (int r = 0; r < 4; r++) o[d][r] *= alpha[r];

        // ---- PV: O += P * V ----
#pragma unroll
        for (int kc = 0; kc < 2; kc++) {
            short8 pf = *(const short8*)(Pw + low * 72 + kc * 32 + quad * 8);
#pragma unroll
            for (int dd = 0; dd < 8; ++dd) {
                const int vr = dd * 16 + low;
                const int cc = kc * 4 + quad;
                short8 vf = *(const short8*)(Vs + vr * 64 + (cc ^ (vr & 7)) * 8);
                o[dd] = __builtin_amdgcn_mfma_f32_16x16x32_bf16(pf, vf, o[dd], 0, 0, 0);
            }
        }
        __syncthreads();  // protect Ks/Vs before next stage
    }

    const int b = bh >> 4, h = bh & 15;
#pragma unroll
    for (int r = 0; r < 4; r++) {
        float inv = 1.0f / l_i[r];
        size_t row = (size_t)(b * TSEQ + q0 + quad * 4 + r);
        u16* yp = y + row * 2048 + h * HDIM;
#pragma unroll
        for (int d = 0; d < 8; ++d) yp[d * 16 + low] = f2bf(o[d][r] * inv);
    }
}

extern "C" void kernel_launch(void* const* d_in, const int* in_sizes, int n_in,
                              void* d_out, int out_size, void* d_ws, size_t ws_size,
                              hipStream_t stream) {
    const float* x = (const float*)d_in[0];
    const float* Wa = (const float*)d_in[1];
    const float* ba = (const float*)d_in[2];
    const float* Wp = (const float*)d_in[3];
    const float* bp = (const float*)d_in[4];
    const float* cs = (const float*)d_in[5];
    const float* sn = (const float*)d_in[6];
    float* out = (float*)d_out;

    u16* xb = (u16*)d_ws;             // x bf16; reused later as y
    u16* Wab = xb + 8388608;
    u16* Wpb = Wab + 12582912;
    u16* qb = Wpb + 4194304;
    u16* kb = qb + 8388608;
    u16* vtmp = kb + 8388608;
    u16* vT = vtmp + 8388608;
    u16* y = xb;

    cast_bf16<<<8192, 256, 0, stream>>>((const float4*)x, (ushort4*)xb, 2097152);
    transpose_cast<<<dim3(96, 32), 256, 0, stream>>>(Wa, Wab, 2048, 6144);
    transpose_cast<<<dim3(32, 32), 256, 0, stream>>>(Wp, Wpb, 2048, 2048);
    gemm_bt<0><<<dim3(48, 32), 256, 0, stream>>>(xb, Wab, ba, nullptr, qb, kb, vtmp, 4096, 6144, 2048);
    rope_inplace<<<16384, 256, 0, stream>>>(qb, kb, cs, sn);
    vtrans<<<2048, 256, 0, stream>>>(vtmp, vT);
    flash_attn<<<dim3(32, 32), 256, 0, stream>>>(qb, kb, vT, y);
    gemm_bt<1><<<dim3(16, 32), 256, 0, stream>>>(y, Wpb, bp, out, nullptr, nullptr, nullptr, 4096, 2048, 2048);
}

// Round 3
// 455.589 us; speedup vs baseline: 1.4866x; 1.0179x over previous
//
#include <hip/hip_runtime.h>

typedef unsigned short u16;
typedef __attribute__((ext_vector_type(8))) short short8;
typedef __attribute__((ext_vector_type(4))) float f32x4;

// Problem constants: B=2, T=2048, C=2048, H=16, HD=128
#define TSEQ 2048
#define NHEAD 16
#define HDIM 128

__device__ __forceinline__ u16 f2bf(float x) {
    unsigned u = __float_as_uint(x);
    return (u16)((u + 0x7fffu + ((u >> 16) & 1u)) >> 16);
}
__device__ __forceinline__ float b2f(u16 h) {
    return __uint_as_float(((unsigned)h) << 16);
}
__device__ __forceinline__ void async16(const void* g, void* l) {
    __builtin_amdgcn_global_load_lds((__attribute__((address_space(1))) void*)(void*)g,
                                     (__attribute__((address_space(3))) void*)l, 16, 0, 0);
}
__device__ __forceinline__ f32x4 zero4() {
    f32x4 z = {0.f, 0.f, 0.f, 0.f};
    return z;
}

// DPP cross-lane (16-lane group reductions), no LDS traffic
template <int CTRL>
__device__ __forceinline__ float dppf(float x) {
    return __int_as_float(__builtin_amdgcn_mov_dpp(__float_as_int(x), CTRL, 0xf, 0xf, true));
}
__device__ __forceinline__ float dpp_max16(float x) {
    x = fmaxf(x, dppf<0xB1>(x));   // quad_perm xor1
    x = fmaxf(x, dppf<0x4E>(x));   // quad_perm xor2
    x = fmaxf(x, dppf<0x141>(x));  // row_half_mirror (~xor4)
    x = fmaxf(x, dppf<0x140>(x));  // row_mirror (~xor8)
    return x;
}
__device__ __forceinline__ float dpp_sum16(float x) {
    x += dppf<0xB1>(x);
    x += dppf<0x4E>(x);
    x += dppf<0x141>(x);
    x += dppf<0x140>(x);
    return x;
}

// ---------------- cast x (f32 -> bf16), vectorized ----------------
__global__ void cast_bf16(const float4* __restrict__ in, ushort4* __restrict__ out, int n4) {
    int i = blockIdx.x * 256 + threadIdx.x;
    if (i < n4) {
        float4 v = in[i];
        ushort4 o;
        o.x = f2bf(v.x); o.y = f2bf(v.y); o.z = f2bf(v.z); o.w = f2bf(v.w);
        out[i] = o;
    }
}

// ---------------- transpose + cast: in f32 [K][N] -> out bf16 [N][K] ----------------
__global__ void transpose_cast(const float* __restrict__ in, u16* __restrict__ out, int K, int N) {
    __shared__ float tile[64][65];
    int n0 = blockIdx.x * 64, k0 = blockIdx.y * 64;
    int tx = threadIdx.x & 63, ty = threadIdx.x >> 6;
#pragma unroll
    for (int i = 0; i < 16; i++) {
        int r = ty + i * 4;
        tile[r][tx] = in[(size_t)(k0 + r) * N + n0 + tx];
    }
    __syncthreads();
#pragma unroll
    for (int i = 0; i < 16; i++) {
        int r = ty + i * 4;
        out[(size_t)(n0 + r) * K + k0 + tx] = f2bf(tile[tx][r]);
    }
}

// ---------------- GEMM: C = A(MxK) * Bt(NxK)^T + bias ----------------
// MODE 0: n-tile == one head (HDIM=128). Epilogue transposes through LDS to
//         contiguous coalesced stores; fuses RoPE for q/k; writes v directly
//         to vT [bh][d][t].
// MODE 1: f32 out row-major [M][N]
template <int MODE>
__global__ __launch_bounds__(256) void gemm_bt(
    const u16* __restrict__ A, const u16* __restrict__ Bt, const float* __restrict__ bias,
    float* __restrict__ outf, u16* __restrict__ qb, u16* __restrict__ kb, u16* __restrict__ vT,
    const float* __restrict__ cosp, const float* __restrict__ sinp,
    int M, int N, int K) {
    __shared__ __align__(16) u16 smem[8704];  // 17408 B: staging (16K) / epilogue tile [64][136]
    u16* As = smem;            // 128*32 u16
    u16* Bs = smem + 4096;     // 128*32 u16
    const int tid = threadIdx.x;
    const int wave = tid >> 6, lane = tid & 63;
    const int low = lane & 15, quad = lane >> 4;
    const int m0 = blockIdx.y * 128, n0 = blockIdx.x * 128;
    const int wm = (wave >> 1) * 64, wn = (wave & 1) * 64;
    const int ldr = lane >> 2;
    const int ldc = (lane & 3) * 8;

    f32x4 acc[4][4];
#pragma unroll
    for (int i = 0; i < 4; i++)
#pragma unroll
        for (int j = 0; j < 4; j++) acc[i][j] = zero4();

    for (int k0 = 0; k0 < K; k0 += 32) {
#pragma unroll
        for (int c = 0; c < 2; ++c) {
            const int chunk = wave * 2 + c;
            const int row = chunk * 16 + ldr;
            async16(A + (size_t)(m0 + row) * K + k0 + ldc, As + chunk * 512);
            async16(Bt + (size_t)(n0 + row) * K + k0 + ldc, Bs + chunk * 512);
        }
        __syncthreads();
        short8 af[4], bfv[4];
#pragma unroll
        for (int i = 0; i < 4; i++) af[i] = *(const short8*)(As + (wm + i * 16 + low) * 32 + quad * 8);
#pragma unroll
        for (int j = 0; j < 4; j++) bfv[j] = *(const short8*)(Bs + (wn + j * 16 + low) * 32 + quad * 8);
#pragma unroll
        for (int i = 0; i < 4; i++)
#pragma unroll
            for (int j = 0; j < 4; j++)
                acc[i][j] = __builtin_amdgcn_mfma_f32_16x16x32_bf16(af[i], bfv[j], acc[i][j], 0, 0, 0);
        __syncthreads();
    }

    if (MODE == 1) {
#pragma unroll
        for (int j = 0; j < 4; j++) {
            const int ng = n0 + wn + j * 16 + low;
            const float bv = bias[ng];
#pragma unroll
            for (int i = 0; i < 4; i++) {
                const int rbase = m0 + wm + i * 16 + quad * 4;
#pragma unroll
                for (int r = 0; r < 4; r++)
                    outf[(size_t)(rbase + r) * N + ng] = acc[i][j][r] + bv;
            }
        }
        return;
    }

    // ---- MODE 0 epilogue ----
    const int which = n0 >> 11;                // 0=q 1=k 2=v
    const int h = (n0 & 2047) >> 7;
    const int b = m0 >> 11, t0 = m0 & 2047;
    float bv[4];
#pragma unroll
    for (int j = 0; j < 4; j++) bv[j] = bias[n0 + wn + j * 16 + low];
    u16* epi = smem;  // [64][136] bf16

    if (which < 2) {
        // q or k: [bh][t][d] contiguous tile, rope fused
        u16* dst = (which == 0 ? qb : kb) + (((size_t)(b * NHEAD + h)) * TSEQ + t0) * HDIM;
#pragma unroll
        for (int pass = 0; pass < 2; pass++) {
            if ((wave >> 1) == pass) {
#pragma unroll
                for (int i = 0; i < 4; i++)
#pragma unroll
                    for (int j = 0; j < 4; j++)
#pragma unroll
                        for (int r = 0; r < 4; r++)
                            epi[(i * 16 + quad * 4 + r) * 136 + wn + j * 16 + low] =
                                f2bf(acc[i][j][r] + bv[j]);
            }
            __syncthreads();
            const int row = tid >> 2, dp = (tid & 3) * 32;
            const int t = t0 + pass * 64 + row;
            u16 vals[32];
#pragma unroll
            for (int q = 0; q < 4; q++)
                *(short8*)(vals + q * 8) = *(const short8*)(epi + row * 136 + dp + q * 8);
            float cs4[16], sn4[16];
#pragma unroll
            for (int q = 0; q < 4; q++) {
                *(float4*)(cs4 + q * 4) = *(const float4*)(cosp + (size_t)t * 64 + (dp >> 1) + q * 4);
                *(float4*)(sn4 + q * 4) = *(const float4*)(sinp + (size_t)t * 64 + (dp >> 1) + q * 4);
            }
            u16 outv[32];
#pragma unroll
            for (int p = 0; p < 16; p++) {
                float x0 = b2f(vals[2 * p]), x1 = b2f(vals[2 * p + 1]);
                outv[2 * p] = f2bf(x0 * cs4[p] - x1 * sn4[p]);
                outv[2 * p + 1] = f2bf(x0 * sn4[p] + x1 * cs4[p]);
            }
            u16* dr = dst + (size_t)(pass * 64 + row) * HDIM + dp;
#pragma unroll
            for (int q = 0; q < 4; q++)
                *(short8*)(dr + q * 8) = *(const short8*)(outv + q * 8);
            __syncthreads();
        }
    } else {
        // v: write transposed [bh][d][t]; LDS tile holds [d-rel 64][t 128+pad]
        u16* dst = vT + ((size_t)(b * NHEAD + h)) * HDIM * TSEQ + t0;
#pragma unroll
        for (int pass = 0; pass < 2; pass++) {
            if ((wave & 1) == pass) {  // wn == pass*64
#pragma unroll
                for (int i = 0; i < 4; i++)
#pragma unroll
                    for (int j = 0; j < 4; j++)
#pragma unroll
                        for (int r = 0; r < 4; r++)
                            epi[(j * 16 + low) * 136 + wm + i * 16 + quad * 4 + r] =
                                f2bf(acc[i][j][r] + bv[j]);
            }
            __syncthreads();
            const int drow = tid >> 2, tc = (tid & 3) * 32;
            u16* dr = dst + (size_t)(pass * 64 + drow) * TSEQ + tc;
#pragma unroll
            for (int q = 0; q < 4; q++)
                *(short8*)(dr + q * 8) = *(const short8*)(epi + drow * 136 + tc + q * 8);
            __syncthreads();
        }
    }
}

// ---------------- Flash attention: LDS-staged K/V, 64-key tiles, DPP softmax ----------------
__global__ __launch_bounds__(256) void flash_attn(const u16* __restrict__ qb, const u16* __restrict__ kb,
                                                  const u16* __restrict__ vT, u16* __restrict__ y) {
    __shared__ u16 Ks[64 * 128];      // [key][d], chunks xor-swizzled by (key&7)
    __shared__ u16 Vs[128 * 64];      // [d][key], chunks xor-swizzled by (d&7)
    __shared__ u16 Ps[4][16 * 72];    // per-wave P 16x64, row stride 72
    const int tid = threadIdx.x;
    const int wave = tid >> 6, lane = tid & 63;
    const int low = lane & 15, quad = lane >> 4;
    const int bh = blockIdx.x;
    const int qt = 31 - blockIdx.y;          // longest blocks first
    const int q0 = qt * 64 + wave * 16;
    const float scale2 = 0.08838834764831845f * 1.44269504088896f;  // 1/sqrt(128) * log2(e)

    const u16* Qp = qb + ((size_t)bh * TSEQ + q0) * HDIM;
    short8 qf[4];
#pragma unroll
    for (int c = 0; c < 4; c++) qf[c] = *(const short8*)(Qp + (size_t)low * HDIM + c * 32 + quad * 8);

    f32x4 o[8];
#pragma unroll
    for (int d = 0; d < 8; d++) o[d] = zero4();
    float m_i[4], l_i[4];
#pragma unroll
    for (int r = 0; r < 4; r++) { m_i[r] = -1e30f; l_i[r] = 0.f; }

    const u16* Kb = kb + (size_t)bh * TSEQ * HDIM;
    const u16* Vb = vT + (size_t)bh * HDIM * TSEQ;
    u16* Pw = &Ps[wave][0];
    const int ntiles = qt + 1;

    const int krow = tid >> 4, kchunk = tid & 15;   // K: 16 rows x 16 chunks per issue
    const int vrow = tid >> 3, vchunk = tid & 7;    // V: 32 rows x 8 chunks per issue

    for (int kt = 0; kt < ntiles; ++kt) {
        const int kv0 = kt * 64;
#pragma unroll
        for (int j = 0; j < 4; j++) {
            const int row = j * 16 + krow;
            const int gc = kchunk ^ (row & 7);
            async16(Kb + (size_t)(kv0 + row) * HDIM + gc * 8, Ks + row * 128 + kchunk * 8);
        }
#pragma unroll
        for (int j = 0; j < 4; j++) {
            const int d = j * 32 + vrow;
            const int gc = vchunk ^ (d & 7);
            async16(Vb + (size_t)d * TSEQ + kv0 + gc * 8, Vs + d * 64 + vchunk * 8);
        }
        __syncthreads();

        // ---- QK^T: S[16q x 64k] ----
        f32x4 s[4];
#pragma unroll
        for (int h = 0; h < 4; h++) s[h] = zero4();
#pragma unroll
        for (int h = 0; h < 4; h++) {
            const int row = h * 16 + low;
#pragma unroll
            for (int c = 0; c < 4; c++) {
                const int cc = c * 4 + quad;
                short8 kf = *(const short8*)(Ks + row * 128 + (cc ^ (row & 7)) * 8);
                s[h] = __builtin_amdgcn_mfma_f32_16x16x32_bf16(qf[c], kf, s[h], 0, 0, 0);
            }
        }

        // ---- online softmax (exp2 domain), DPP reductions ----
        float alpha[4];
#pragma unroll
        for (int r = 0; r < 4; r++) {
            const int qg = q0 + quad * 4 + r;
            float sv[4];
#pragma unroll
            for (int h = 0; h < 4; h++)
                sv[h] = (kv0 + h * 16 + low <= qg) ? s[h][r] * scale2 : -1e30f;
            float mx = fmaxf(fmaxf(sv[0], sv[1]), fmaxf(sv[2], sv[3]));
            mx = dpp_max16(mx);
            float mnew = fmaxf(m_i[r], mx);
            alpha[r] = exp2f(m_i[r] - mnew);
            m_i[r] = mnew;
            float p0 = exp2f(sv[0] - mnew);
            float p1 = exp2f(sv[1] - mnew);
            float p2 = exp2f(sv[2] - mnew);
            float p3 = exp2f(sv[3] - mnew);
            float rs = (p0 + p1) + (p2 + p3);
            rs = dpp_sum16(rs);
            l_i[r] = l_i[r] * alpha[r] + rs;
            const int prow = (quad * 4 + r) * 72;
            Pw[prow + low] = f2bf(p0);
            Pw[prow + 16 + low] = f2bf(p1);
            Pw[prow + 32 + low] = f2bf(p2);
            Pw[prow + 48 + low] = f2bf(p3);
        }
        __threadfence_block();

#pragma unroll
        for (int d = 0; d < 8; ++d)
#pragma unroll
            for (int r = 0; r < 4; r++) o[d][r] *= alpha[r];

        // ---- PV ----
#pragma unroll
        for (int kc = 0; kc < 2; kc++) {
            short8 pf = *(const short8*)(Pw + low * 72 + kc * 32 + quad * 8);
#pragma unroll
            for (int dd = 0; dd < 8; ++dd) {
                const int vr = dd * 16 + low;
                const int cc = kc * 4 + quad;
                short8 vf = *(const short8*)(Vs + vr * 64 + (cc ^ (vr & 7)) * 8);
                o[dd] = __builtin_amdgcn_mfma_f32_16x16x32_bf16(pf, vf, o[dd], 0, 0, 0);
            }
        }
        __syncthreads();
    }

    const int b = bh >> 4, h = bh & 15;
#pragma unroll
    for (int r = 0; r < 4; r++) {
        float inv = 1.0f / l_i[r];
        size_t row = (size_t)(b * TSEQ + q0 + quad * 4 + r);
        u16* yp = y + row * 2048 + h * HDIM;
#pragma unroll
        for (int d = 0; d < 8; ++d) yp[d * 16 + low] = f2bf(o[d][r] * inv);
    }
}

extern "C" void kernel_launch(void* const* d_in, const int* in_sizes, int n_in,
                              void* d_out, int out_size, void* d_ws, size_t ws_size,
                              hipStream_t stream) {
    const float* x = (const float*)d_in[0];
    const float* Wa = (const float*)d_in[1];
    const float* ba = (const float*)d_in[2];
    const float* Wp = (const float*)d_in[3];
    const float* bp = (const float*)d_in[4];
    const float* cs = (const float*)d_in[5];
    const float* sn = (const float*)d_in[6];
    float* out = (float*)d_out;

    u16* xb = (u16*)d_ws;             // x bf16; reused later as y
    u16* Wab = xb + 8388608;          // W_attn^T bf16 [6144][2048]
    u16* Wpb = Wab + 12582912;        // W_proj^T bf16 [2048][2048]
    u16* qb = Wpb + 4194304;          // [bh][t][d]
    u16* kb = qb + 8388608;           // [bh][t][d]
    u16* vT = kb + 8388608;           // [bh][d][t]
    u16* y = xb;

    cast_bf16<<<8192, 256, 0, stream>>>((const float4*)x, (ushort4*)xb, 2097152);
    transpose_cast<<<dim3(96, 32), 256, 0, stream>>>(Wa, Wab, 2048, 6144);
    transpose_cast<<<dim3(32, 32), 256, 0, stream>>>(Wp, Wpb, 2048, 2048);
    gemm_bt<0><<<dim3(48, 32), 256, 0, stream>>>(xb, Wab, ba, nullptr, qb, kb, vT, cs, sn, 4096, 6144, 2048);
    flash_attn<<<dim3(32, 32), 256, 0, stream>>>(qb, kb, vT, y);
    gemm_bt<1><<<dim3(16, 32), 256, 0, stream>>>(y, Wpb, bp, out, nullptr, nullptr, nullptr, nullptr, nullptr, 4096, 2048, 2048);
}